// Round 2
// baseline (498.354 us; speedup 1.0000x reference)
//
#include <hip/hip_runtime.h>
#include <hip/hip_bf16.h>
#include <cstdint>
#include <cstddef>

typedef __hip_bfloat16 bf16;
typedef __attribute__((ext_vector_type(8))) short short8;
typedef __attribute__((ext_vector_type(4))) float floatx4;

__constant__ int c_H0[6] = {0,0,0,1,1,2};
__constant__ int c_H1[6] = {1,2,3,2,3,3};
__constant__ int c_B0[10] = {0,0,0,0,0,0,1,1,1,2};
__constant__ int c_B1[10] = {1,1,1,2,2,3,2,2,3,3};
__constant__ int c_B2[10] = {2,3,4,3,4,4,3,4,4,4};

__device__ __forceinline__ float lrelu(float v) { return v > 0.f ? v : 0.01f * v; }

// ---- transpose+convert: W (K x 256, row-major, f32) -> Wt (256 x K, row-major, bf16)
__global__ __launch_bounds__(256) void transpose_k(const float* __restrict__ W,
                                                   bf16* __restrict__ Wt, int K)
{
  __shared__ float tile[64][65];
  const int kb = blockIdx.x * 64;
  const int nb = blockIdx.y * 64;
  const int t = threadIdx.x;
  #pragma unroll
  for (int i = 0; i < 16; ++i) {
    int idx = t + 256 * i;
    int r = idx >> 6, c = idx & 63;
    tile[r][c] = W[(size_t)(kb + r) * 256 + nb + c];
  }
  __syncthreads();
  #pragma unroll
  for (int i = 0; i < 16; ++i) {
    int idx = t + 256 * i;
    int r = idx >> 6, c = idx & 63;
    Wt[(size_t)(nb + r) * K + kb + c] = __float2bfloat16(tile[c][r]);
  }
}

// ---- per-item: embeddings + hand + board (VALU, f32) + hidden layer (MFMA bf16) -> h (bf16)
__global__ __launch_bounds__(256) void item_kernel(
    const int* __restrict__ x,
    const float* __restrict__ card_emb,
    const float* __restrict__ hand_W, const float* __restrict__ hand_b,
    const float* __restrict__ board_W, const float* __restrict__ board_b,
    const bf16* __restrict__ hWt, const float* __restrict__ hidden_b,
    bf16* __restrict__ h_out)
{
  __shared__ float emb[9][16];
  __shared__ float biasH[256];
  __shared__ bf16 A[64][264];   // 60 used rows; stride 264 (2-way bank alias = free)

  const int t = threadIdx.x;
  const int item = blockIdx.x;

  if (t < 144) {
    int ci = t >> 4, e = t & 15;
    int rk = x[item * 18 + 2 * ci];
    int st = x[item * 18 + 2 * ci + 1];
    int card = (rk > 0 ? rk - 1 : 0) + (st > 0 ? (st - 1) * 13 : 0);
    emb[ci][e] = card_emb[card * 16 + e];
  }
  biasH[t] = hidden_b[t];
  {
    bf16 z = __float2bfloat16(0.f);
    for (int idx = t; idx < 4 * 264; idx += 256)
      A[60 + idx / 264][idx % 264] = z;
  }
  __syncthreads();

  // hero: 6 pairs x 128 outputs (p is wave-uniform)
  #pragma unroll
  for (int i = 0; i < 3; ++i) {
    int idx = t + 256 * i;          // 0..767
    int p = idx >> 7, j = idx & 127;
    int c0 = c_H0[p], c1 = c_H1[p];
    float acc = hand_b[j];
    #pragma unroll
    for (int k = 0; k < 16; ++k)
      acc += emb[c0][k] * hand_W[k * 128 + j];
    #pragma unroll
    for (int k = 0; k < 16; ++k)
      acc += emb[c1][k] * hand_W[(16 + k) * 128 + j];
    bf16 hv = __float2bfloat16(lrelu(acc));
    #pragma unroll
    for (int q = 0; q < 10; ++q) A[p * 10 + q][j] = hv;   // combo = p*10 + q
  }
  // board: 10 triples x 128 outputs (b is wave-uniform)
  #pragma unroll
  for (int i = 0; i < 5; ++i) {
    int idx = t + 256 * i;          // 0..1279
    int b = idx >> 7, j = idx & 127;
    int c0 = c_B0[b], c1 = c_B1[b], c2 = c_B2[b];
    float acc = board_b[j];
    #pragma unroll
    for (int k = 0; k < 16; ++k) {
      acc += emb[4 + c0][k] * board_W[k * 128 + j];
      acc += emb[4 + c1][k] * board_W[(16 + k) * 128 + j];
      acc += emb[4 + c2][k] * board_W[(32 + k) * 128 + j];
    }
    bf16 hv = __float2bfloat16(lrelu(acc));
    #pragma unroll
    for (int p = 0; p < 6; ++p) A[p * 10 + b][128 + j] = hv;  // combo = p*10 + b
  }
  __syncthreads();

  // hidden layer MFMA: D(64x256) = A(64x256) @ hidden_W(256x256)
  const int w = t >> 6, l = t & 63;
  const int lr = l & 15, quad = l >> 4;

  floatx4 acc[16];
  floatx4 zero = {0.f, 0.f, 0.f, 0.f};
  #pragma unroll
  for (int i = 0; i < 16; ++i) acc[i] = zero;

  #pragma unroll
  for (int ks = 0; ks < 8; ++ks) {
    short8 a = *(const short8*)(&A[16 * w + lr][ks * 32 + quad * 8]);
    #pragma unroll
    for (int tl = 0; tl < 16; ++tl) {
      short8 b = *(const short8*)(hWt + (size_t)(16 * tl + lr) * 256 + ks * 32 + quad * 8);
      acc[tl] = __builtin_amdgcn_mfma_f32_16x16x32_bf16(a, b, acc[tl], 0, 0, 0);
    }
  }

  const size_t base = (size_t)item * 15360;
  #pragma unroll
  for (int tl = 0; tl < 16; ++tl) {
    int n = 16 * tl + lr;
    float bn = biasH[n];
    #pragma unroll
    for (int r = 0; r < 4; ++r) {
      int m = 16 * w + quad * 4 + r;   // combo row
      if (m < 60)
        h_out[base + (size_t)m * 256 + n] = __float2bfloat16(lrelu(acc[tl][r] + bn));
    }
  }
}

// ---- out layer GEMM: (NI x 15360) @ oWt^T -> (NI x 256) f32, 64x64 tiles
#define KO 15360
__global__ __launch_bounds__(256) void out_gemm(
    const bf16* __restrict__ Ah, const bf16* __restrict__ Wt,
    const float* __restrict__ outb, float* __restrict__ out)
{
  __shared__ bf16 As[64][72];
  __shared__ bf16 Bs[64][72];
  __shared__ float biasO[64];

  const int t = threadIdx.x;
  const int m0 = blockIdx.x * 64;
  const int n0 = blockIdx.y * 64;
  if (t < 64) biasO[t] = outb[n0 + t];

  const int row = t >> 2;
  const int c0 = (t & 3) * 16;
  const int w = t >> 6, l = t & 63, lr = l & 15, quad = l >> 4;

  floatx4 acc[4];
  floatx4 zero = {0.f, 0.f, 0.f, 0.f};
  #pragma unroll
  for (int i = 0; i < 4; ++i) acc[i] = zero;

  const bf16* aSrc = Ah + (size_t)(m0 + row) * KO + c0;
  const bf16* bSrc = Wt + (size_t)(n0 + row) * KO + c0;

  for (int s = 0; s < KO; s += 64) {
    short8 a0 = *(const short8*)(aSrc + s);
    short8 a1 = *(const short8*)(aSrc + s + 8);
    short8 b0 = *(const short8*)(bSrc + s);
    short8 b1 = *(const short8*)(bSrc + s + 8);
    *(short8*)(&As[row][c0])     = a0;
    *(short8*)(&As[row][c0 + 8]) = a1;
    *(short8*)(&Bs[row][c0])     = b0;
    *(short8*)(&Bs[row][c0 + 8]) = b1;
    __syncthreads();
    #pragma unroll
    for (int ks = 0; ks < 64; ks += 32) {
      short8 a = *(const short8*)(&As[16 * w + lr][ks + quad * 8]);
      #pragma unroll
      for (int tl = 0; tl < 4; ++tl) {
        short8 b = *(const short8*)(&Bs[16 * tl + lr][ks + quad * 8]);
        acc[tl] = __builtin_amdgcn_mfma_f32_16x16x32_bf16(a, b, acc[tl], 0, 0, 0);
      }
    }
    __syncthreads();
  }

  #pragma unroll
  for (int tl = 0; tl < 4; ++tl) {
    int n = n0 + 16 * tl + lr;
    float bn = biasO[16 * tl + lr];
    #pragma unroll
    for (int r = 0; r < 4; ++r) {
      int m = m0 + 16 * w + quad * 4 + r;
      out[(size_t)m * 256 + n] = lrelu(acc[tl][r] + bn);
    }
  }
}

extern "C" void kernel_launch(void* const* d_in, const int* in_sizes, int n_in,
                              void* d_out, int out_size, void* d_ws, size_t ws_size,
                              hipStream_t stream)
{
  const int*   x        = (const int*)  d_in[0];
  const float* card_emb = (const float*)d_in[1];
  const float* hand_W   = (const float*)d_in[2];
  const float* hand_b   = (const float*)d_in[3];
  const float* board_W  = (const float*)d_in[4];
  const float* board_b  = (const float*)d_in[5];
  const float* hidden_W = (const float*)d_in[6];
  const float* hidden_b = (const float*)d_in[7];
  const float* out_W    = (const float*)d_in[8];
  const float* out_b    = (const float*)d_in[9];
  float* out = (float*)d_out;

  char* ws = (char*)d_ws;
  bf16* hWt = (bf16*)ws;                                        // 256*256 bf16
  bf16* oWt = (bf16*)(ws + 256 * 256 * 2);                      // 256*15360 bf16
  bf16* h   = (bf16*)(ws + 256 * 256 * 2 + 256 * 15360 * 2);    // NI*15360 bf16

  const int NI = in_sizes[0] / 18;   // 3072 items

  transpose_k<<<dim3(4, 4),   256, 0, stream>>>(hidden_W, hWt, 256);
  transpose_k<<<dim3(240, 4), 256, 0, stream>>>(out_W,    oWt, 15360);
  item_kernel<<<NI, 256, 0, stream>>>(x, card_emb, hand_W, hand_b,
                                      board_W, board_b, hWt, hidden_b, h);
  out_gemm<<<dim3(NI / 64, 4), 256, 0, stream>>>(h, oWt, out_b, out);
}

// Round 3
// 260.110 us; speedup vs baseline: 1.9159x; 1.9159x over previous
//
#include <hip/hip_runtime.h>
#include <hip/hip_bf16.h>
#include <cstdint>
#include <cstddef>

typedef __hip_bfloat16 bf16;
typedef __attribute__((ext_vector_type(8))) short short8;
typedef __attribute__((ext_vector_type(4))) float floatx4;

__device__ __forceinline__ float lrelu(float v) { return v > 0.f ? v : 0.01f * v; }

__device__ __forceinline__ float bflo(unsigned int u) {
  unsigned int x = u << 16; float f; __builtin_memcpy(&f, &x, 4); return f;
}
__device__ __forceinline__ float bfhi(unsigned int u) {
  unsigned int x = u & 0xffff0000u; float f; __builtin_memcpy(&f, &x, 4); return f;
}
__device__ __forceinline__ unsigned int pk2(float lo, float hi) {
  bf16 a = __float2bfloat16(lo), b = __float2bfloat16(hi);
  unsigned short ua, ub;
  __builtin_memcpy(&ua, &a, 2); __builtin_memcpy(&ub, &b, 2);
  return (unsigned int)ua | ((unsigned int)ub << 16);
}

// ---- transpose+convert: W (K x 256, row-major, f32) -> Wt (256 x K, row-major, bf16)
__global__ __launch_bounds__(256) void transpose_k(const float* __restrict__ W,
                                                   bf16* __restrict__ Wt, int K)
{
  __shared__ float tile[64][65];
  const int kb = blockIdx.x * 64;
  const int nb = blockIdx.y * 64;
  const int t = threadIdx.x;
  #pragma unroll
  for (int i = 0; i < 16; ++i) {
    int idx = t + 256 * i;
    int r = idx >> 6, c = idx & 63;
    tile[r][c] = W[(size_t)(kb + r) * 256 + nb + c];
  }
  __syncthreads();
  #pragma unroll
  for (int i = 0; i < 16; ++i) {
    int idx = t + 256 * i;
    int r = idx >> 6, c = idx & 63;
    Wt[(size_t)(nb + r) * K + kb + c] = __float2bfloat16(tile[c][r]);
  }
}

// ---- per-item factorized hidden: U_p = hero_p @ Wh_top, V_b = board_b @ Wh_bot,
//      h[p*10+b] = lrelu(U_p + V_b + bias). One wave = one item, 4 items/block.
__global__ __launch_bounds__(256) void item_kernel(
    const int* __restrict__ x, const float* __restrict__ card_emb,
    const float* __restrict__ hand_W, const float* __restrict__ hand_b,
    const float* __restrict__ board_W, const float* __restrict__ board_b,
    const bf16* __restrict__ hWt, const float* __restrict__ hidden_b,
    bf16* __restrict__ h_out)
{
  static constexpr int H0[6] = {0,0,0,1,1,2};
  static constexpr int H1[6] = {1,2,3,2,3,3};
  static constexpr int B0[10] = {0,0,0,0,0,0,1,1,1,2};
  static constexpr int B1[10] = {1,1,1,2,2,3,2,2,3,3};
  static constexpr int B2[10] = {2,3,4,3,4,4,3,4,4,4};

  __shared__ bf16 A[4][16][264];    // per item: rows 0..5 = [hero_p | 0], 6..15 = [0 | board_b]
  __shared__ float emb[4][9][16];
  __shared__ float biasH[256];

  const int t = threadIdx.x;
  const int w = t >> 6, l = t & 63;
  const int item = blockIdx.x * 4 + w;

  biasH[t] = hidden_b[t];
  __syncthreads();

  // ---- embeddings (wave-local: written & read by wave w only)
  for (int idx = l; idx < 144; idx += 64) {
    int ci = idx >> 4, e = idx & 15;
    int rk = x[item * 18 + 2 * ci], st = x[item * 18 + 2 * ci + 1];
    int card = (rk > 0 ? rk - 1 : 0) + (st > 0 ? (st - 1) * 13 : 0);
    emb[w][ci][e] = card_emb[card * 16 + e];
  }
  // zero halves of A (2 bf16 per 4B write)
  #pragma unroll
  for (int p = 0; p < 6; ++p) *(unsigned int*)&A[w][p][128 + 2 * l] = 0u;
  #pragma unroll
  for (int b = 0; b < 10; ++b) *(unsigned int*)&A[w][6 + b][2 * l] = 0u;

  // ---- hero (6x128) + board (10x128), 2 output cols per lane
  #pragma unroll
  for (int jj = 0; jj < 2; ++jj) {
    const int j = jj * 64 + l;
    float wh[32], wb[48];
    #pragma unroll
    for (int k = 0; k < 32; ++k) wh[k] = hand_W[k * 128 + j];
    #pragma unroll
    for (int k = 0; k < 48; ++k) wb[k] = board_W[k * 128 + j];
    float aH[6], aB[10];
    {
      float hb = hand_b[j], bb = board_b[j];
      #pragma unroll
      for (int p = 0; p < 6; ++p) aH[p] = hb;
      #pragma unroll
      for (int b = 0; b < 10; ++b) aB[b] = bb;
    }
    #pragma unroll
    for (int k = 0; k < 16; ++k) {
      float e[9];
      #pragma unroll
      for (int c = 0; c < 9; ++c) e[c] = emb[w][c][k];
      #pragma unroll
      for (int p = 0; p < 6; ++p)
        aH[p] += e[H0[p]] * wh[k] + e[H1[p]] * wh[16 + k];
      #pragma unroll
      for (int b = 0; b < 10; ++b)
        aB[b] += e[4 + B0[b]] * wb[k] + e[4 + B1[b]] * wb[16 + k] + e[4 + B2[b]] * wb[32 + k];
    }
    #pragma unroll
    for (int p = 0; p < 6; ++p) A[w][p][j] = __float2bfloat16(lrelu(aH[p]));
    #pragma unroll
    for (int b = 0; b < 10; ++b) A[w][6 + b][128 + j] = __float2bfloat16(lrelu(aB[b]));
  }

  // ---- U/V via MFMA: D(16x256) = A(16x256) @ hidden_W(256x256)
  const int lr = l & 15, quad = l >> 4;
  floatx4 acc[16];
  floatx4 zero = {0.f, 0.f, 0.f, 0.f};
  #pragma unroll
  for (int i = 0; i < 16; ++i) acc[i] = zero;

  #pragma unroll
  for (int ks = 0; ks < 8; ++ks) {
    short8 a = *(const short8*)&A[w][lr][ks * 32 + quad * 8];
    #pragma unroll
    for (int tl = 0; tl < 16; ++tl) {
      short8 bfrag = *(const short8*)(hWt + (size_t)((tl << 4) + lr) * 256 + ks * 32 + quad * 8);
      acc[tl] = __builtin_amdgcn_mfma_f32_16x16x32_bf16(a, bfrag, acc[tl], 0, 0, 0);
    }
  }

  // write U/V (bf16) in place over A[w]  (wave-local, in-wave LDS ordering is safe)
  #pragma unroll
  for (int tl = 0; tl < 16; ++tl)
    #pragma unroll
    for (int r = 0; r < 4; ++r)
      A[w][quad * 4 + r][(tl << 4) + lr] = __float2bfloat16(acc[tl][r]);

  // ---- h-assembly: h[p*10+b][:] = lrelu(U_p + V_b + biasH), 4 cols/lane
  const floatx4 b4 = *(const floatx4*)&biasH[4 * l];
  bf16* hbase = h_out + (size_t)item * 15360 + 4 * l;
  #pragma unroll
  for (int p = 0; p < 6; ++p) {
    uint2 uu = *(const uint2*)&A[w][p][4 * l];
    float u0 = bflo(uu.x), u1 = bfhi(uu.x), u2 = bflo(uu.y), u3 = bfhi(uu.y);
    #pragma unroll
    for (int b = 0; b < 10; ++b) {
      uint2 vv = *(const uint2*)&A[w][6 + b][4 * l];
      float r0 = lrelu(u0 + bflo(vv.x) + b4[0]);
      float r1 = lrelu(u1 + bfhi(vv.x) + b4[1]);
      float r2 = lrelu(u2 + bflo(vv.y) + b4[2]);
      float r3 = lrelu(u3 + bfhi(vv.y) + b4[3]);
      uint2 pk; pk.x = pk2(r0, r1); pk.y = pk2(r2, r3);
      *(uint2*)(hbase + (p * 10 + b) * 256) = pk;
    }
  }
}

// ---- out layer GEMM with split-K: (3072 x 15360) @ Wt^T -> atomicAdd f32 partials
#define KO 15360
#define KSLICE 960
#define BK 64

__global__ __launch_bounds__(256) void out_gemm(
    const bf16* __restrict__ Ah, const bf16* __restrict__ Wt,
    float* __restrict__ outacc)
{
  __shared__ bf16 As[64][72];
  __shared__ bf16 Bs[256][72];

  const int t = threadIdx.x;
  const int w = t >> 6, l = t & 63;
  const int lr = l & 15, quad = l >> 4;
  const int m0 = blockIdx.x * 64;
  const int ks0 = blockIdx.y * KSLICE;

  const int srow = t >> 3, skc = t & 7;   // staging: row group + 16B chunk
  const bf16* aS = Ah + (size_t)(m0 + srow) * KO + ks0 + skc * 8;
  const bf16* bS = Wt + (size_t)srow * KO + ks0 + skc * 8;

  floatx4 acc[16];
  floatx4 zero = {0.f, 0.f, 0.f, 0.f};
  #pragma unroll
  for (int i = 0; i < 16; ++i) acc[i] = zero;

  for (int it = 0; it < KSLICE / BK; ++it) {
    const int ko = it * BK;
    short8 av[2], bv[8];
    #pragma unroll
    for (int i = 0; i < 2; ++i) av[i] = *(const short8*)(aS + (size_t)i * 32 * KO + ko);
    #pragma unroll
    for (int j = 0; j < 8; ++j) bv[j] = *(const short8*)(bS + (size_t)j * 32 * KO + ko);
    __syncthreads();
    #pragma unroll
    for (int i = 0; i < 2; ++i) *(short8*)&As[i * 32 + srow][skc * 8] = av[i];
    #pragma unroll
    for (int j = 0; j < 8; ++j) *(short8*)&Bs[j * 32 + srow][skc * 8] = bv[j];
    __syncthreads();
    #pragma unroll
    for (int ks = 0; ks < 2; ++ks) {
      short8 af[4], bfr[4];
      #pragma unroll
      for (int i = 0; i < 4; ++i) af[i] = *(const short8*)&As[i * 16 + lr][ks * 32 + quad * 8];
      #pragma unroll
      for (int j = 0; j < 4; ++j) bfr[j] = *(const short8*)&Bs[w * 64 + j * 16 + lr][ks * 32 + quad * 8];
      #pragma unroll
      for (int i = 0; i < 4; ++i)
        #pragma unroll
        for (int j = 0; j < 4; ++j)
          acc[i * 4 + j] = __builtin_amdgcn_mfma_f32_16x16x32_bf16(af[i], bfr[j], acc[i * 4 + j], 0, 0, 0);
    }
  }

  #pragma unroll
  for (int i = 0; i < 4; ++i)
    #pragma unroll
    for (int j = 0; j < 4; ++j)
      #pragma unroll
      for (int r = 0; r < 4; ++r) {
        int m = m0 + i * 16 + quad * 4 + r;
        int n = w * 64 + j * 16 + lr;
        atomicAdd(&outacc[(size_t)m * 256 + n], acc[i * 4 + j][r]);
      }
}

// ---- epilogue: out = lrelu(out + bias)
__global__ __launch_bounds__(256) void bias_act(float* __restrict__ out,
                                                const float* __restrict__ outb)
{
  int idx = blockIdx.x * 256 + threadIdx.x;      // one float4 each
  int n4 = (idx & 63) * 4;
  float4 b = *(const float4*)&outb[n4];
  float4 v = ((float4*)out)[idx];
  v.x = lrelu(v.x + b.x);
  v.y = lrelu(v.y + b.y);
  v.z = lrelu(v.z + b.z);
  v.w = lrelu(v.w + b.w);
  ((float4*)out)[idx] = v;
}

extern "C" void kernel_launch(void* const* d_in, const int* in_sizes, int n_in,
                              void* d_out, int out_size, void* d_ws, size_t ws_size,
                              hipStream_t stream)
{
  const int*   x        = (const int*)  d_in[0];
  const float* card_emb = (const float*)d_in[1];
  const float* hand_W   = (const float*)d_in[2];
  const float* hand_b   = (const float*)d_in[3];
  const float* board_W  = (const float*)d_in[4];
  const float* board_b  = (const float*)d_in[5];
  const float* hidden_W = (const float*)d_in[6];
  const float* hidden_b = (const float*)d_in[7];
  const float* out_W    = (const float*)d_in[8];
  const float* out_b    = (const float*)d_in[9];
  float* out = (float*)d_out;

  char* ws = (char*)d_ws;
  bf16* hWt = (bf16*)ws;                                        // 256*256 bf16
  bf16* oWt = (bf16*)(ws + 256 * 256 * 2);                      // 256*15360 bf16
  bf16* h   = (bf16*)(ws + 256 * 256 * 2 + 256 * 15360 * 2);    // NI*15360 bf16

  const int NI = in_sizes[0] / 18;   // 3072 items

  transpose_k<<<dim3(4, 4),   256, 0, stream>>>(hidden_W, hWt, 256);
  transpose_k<<<dim3(240, 4), 256, 0, stream>>>(out_W,    oWt, 15360);
  item_kernel<<<NI / 4, 256, 0, stream>>>(x, card_emb, hand_W, hand_b,
                                          board_W, board_b, hWt, hidden_b, h);
  hipMemsetAsync(d_out, 0, (size_t)out_size * sizeof(float), stream);
  out_gemm<<<dim3(NI / 64, KO / KSLICE), 256, 0, stream>>>(h, oWt, out);
  bias_act<<<(out_size / 4 + 255) / 256, 256, 0, stream>>>(out, out_b);
}